// Round 10
// baseline (400.180 us; speedup 1.0000x reference)
//
#include <hip/hip_runtime.h>
#include <hip/hip_bf16.h>

#define N_NODES 50000
#define N_EDGES 800000
#define F_IN    128
#define H_DIM   256
#define G_NUM   64
#define A_DIM   8

#define NBUCKET 196                 // dst>>8, dst<50000
#define NCHUNK  391                 // ceil(800000/2048)
#define CHUNK   2048
#define K4CAP   6144                // bucket edge capacity in LDS
#define QN      12500               // pipeline quarter (N_NODES/4)

typedef __attribute__((ext_vector_type(8))) short short8v;
typedef __attribute__((ext_vector_type(4))) float float4v;
typedef __attribute__((ext_vector_type(2))) float float2v;

__device__ __forceinline__ float b2f(unsigned short u) {
    return __uint_as_float(((unsigned int)u) << 16);
}
__device__ __forceinline__ unsigned short f2b(float v) {
    return __hip_bfloat16_raw(__float2bfloat16(v)).x;
}
__device__ __forceinline__ unsigned char f2fp8(float v) {
    return (unsigned char)(__builtin_amdgcn_cvt_pk_fp8_f32(v, v, 0, false) & 0xff);
}
__device__ __forceinline__ unsigned int pack2(float a, float b) {
    return (unsigned int)f2b(a) | ((unsigned int)f2b(b) << 16);
}
// 16 fp8 -> 8 v_pk_add_f32 (inputs pre-scaled by dinv[src])
__device__ __forceinline__ void accadd16(float2v* a, uint4 v) {
    a[0] += __builtin_amdgcn_cvt_pk_f32_fp8((int)v.x, false);
    a[1] += __builtin_amdgcn_cvt_pk_f32_fp8((int)v.x, true);
    a[2] += __builtin_amdgcn_cvt_pk_f32_fp8((int)v.y, false);
    a[3] += __builtin_amdgcn_cvt_pk_f32_fp8((int)v.y, true);
    a[4] += __builtin_amdgcn_cvt_pk_f32_fp8((int)v.z, false);
    a[5] += __builtin_amdgcn_cvt_pk_f32_fp8((int)v.z, true);
    a[6] += __builtin_amdgcn_cvt_pk_f32_fp8((int)v.w, false);
    a[7] += __builtin_amdgcn_cvt_pk_f32_fp8((int)v.w, true);
}
// 16 fp8 -> 8 v_pk_fma_f32 with scalar weight (unscaled input path)
__device__ __forceinline__ void accfma16(float2v* a, uint4 v, float w) {
    float2v w2 = {w, w};
    a[0] = __builtin_amdgcn_cvt_pk_f32_fp8((int)v.x, false) * w2 + a[0];
    a[1] = __builtin_amdgcn_cvt_pk_f32_fp8((int)v.x, true)  * w2 + a[1];
    a[2] = __builtin_amdgcn_cvt_pk_f32_fp8((int)v.y, false) * w2 + a[2];
    a[3] = __builtin_amdgcn_cvt_pk_f32_fp8((int)v.y, true)  * w2 + a[3];
    a[4] = __builtin_amdgcn_cvt_pk_f32_fp8((int)v.z, false) * w2 + a[4];
    a[5] = __builtin_amdgcn_cvt_pk_f32_fp8((int)v.z, true)  * w2 + a[5];
    a[6] = __builtin_amdgcn_cvt_pk_f32_fp8((int)v.w, false) * w2 + a[6];
    a[7] = __builtin_amdgcn_cvt_pk_f32_fp8((int)v.w, true)  * w2 + a[7];
}

#define SK 40

// ---------------- fuse0: [bucket count (LDS hist)] + [GEMM1 X(f32)*W1(f32) -> P fp8 unscaled]
//                  + [Wt2/Wt3 transposes] -- all dependency-free, zero global atomics --------

__global__ __launch_bounds__(512) void fuse0_kernel(const int* __restrict__ dst,
                                                    unsigned int* __restrict__ Hg,
                                                    const float* __restrict__ x,
                                                    const float* __restrict__ W1,
                                                    unsigned char* __restrict__ P8,
                                                    const float* __restrict__ W2,
                                                    unsigned short* __restrict__ Wt2,
                                                    const float* __restrict__ W3,
                                                    unsigned short* __restrict__ Wt3) {
    const int CB = NCHUNK;                 // 391 count blocks
    const int GB = (N_NODES + 127) / 128;  // 391 gemm blocks
    int b = blockIdx.x, t = threadIdx.x;
    if (b < CB) {
        __shared__ unsigned int h[256];
        if (t < 256) h[t] = 0u;
        __syncthreads();
        int base = b * CHUNK;
        #pragma unroll
        for (int k = 0; k < 4; k++) {
            int i = base + k * 512 + t;
            if (i < N_EDGES) atomicAdd(&h[dst[i] >> 8], 1u);
        }
        __syncthreads();
        if (t < 256) Hg[(size_t)t * NCHUNK + b] = h[t];
        return;
    }
    b -= CB;
    if (b < GB) {
        __shared__ unsigned short As[128][SK];
        __shared__ unsigned short Bs[256][SK];
        int wave = t >> 6, lane = t & 63;
        int wm0 = (wave & 1) * 64, wn0 = (wave >> 1) * 64;
        int bm = b * 128;
        int l15 = lane & 15, lq = lane >> 4;
        float4v acc[4][4];
        #pragma unroll
        for (int i = 0; i < 4; i++)
            #pragma unroll
            for (int j = 0; j < 4; j++)
                acc[i][j] = (float4v){0.f, 0.f, 0.f, 0.f};

        for (int k0 = 0; k0 < F_IN; k0 += 32) {
            {
                int row = t >> 2, koff = (t & 3) * 8;
                short8v tmp = (short8v){0,0,0,0,0,0,0,0};
                if (bm + row < N_NODES) {
                    const float* xp = x + (size_t)(bm + row) * F_IN + k0 + koff;
                    float4 a0 = *(const float4*)xp;
                    float4 a1 = *(const float4*)(xp + 4);
                    tmp[0] = (short)f2b(a0.x); tmp[1] = (short)f2b(a0.y);
                    tmp[2] = (short)f2b(a0.z); tmp[3] = (short)f2b(a0.w);
                    tmp[4] = (short)f2b(a1.x); tmp[5] = (short)f2b(a1.y);
                    tmp[6] = (short)f2b(a1.z); tmp[7] = (short)f2b(a1.w);
                }
                *(short8v*)&As[row][koff] = tmp;
            }
            #pragma unroll
            for (int h = 0; h < 2; h++) {
                int c = t + h * 512;
                int n = c >> 2, koff = (c & 3) * 8;
                short8v tmp;
                #pragma unroll
                for (int kk = 0; kk < 8; kk++)
                    tmp[kk] = (short)f2b(W1[(size_t)(k0 + koff + kk) * H_DIM + n]);
                *(short8v*)&Bs[n][koff] = tmp;
            }
            __syncthreads();
            short8v af[4], bf[4];
            #pragma unroll
            for (int i = 0; i < 4; i++) {
                af[i] = *(const short8v*)&As[wm0 + i * 16 + l15][lq * 8];
                bf[i] = *(const short8v*)&Bs[wn0 + i * 16 + l15][lq * 8];
            }
            #pragma unroll
            for (int i = 0; i < 4; i++)
                #pragma unroll
                for (int j = 0; j < 4; j++)
                    acc[i][j] = __builtin_amdgcn_mfma_f32_16x16x32_bf16(af[i], bf[j], acc[i][j], 0, 0, 0);
            __syncthreads();
        }
        #pragma unroll
        for (int i = 0; i < 4; i++) {
            #pragma unroll
            for (int r = 0; r < 4; r++) {
                int row = bm + wm0 + i * 16 + lq * 4 + r;
                if (row < N_NODES) {
                    #pragma unroll
                    for (int j = 0; j < 4; j++) {
                        int col = wn0 + j * 16 + l15;
                        P8[(size_t)row * H_DIM + col] = f2fp8(acc[i][j][r]);
                    }
                }
            }
        }
        return;
    }
    b -= GB;
    int i = b * 512 + t;
    if (i < H_DIM * H_DIM) {
        int k = i >> 8, n = i & 255;
        Wt2[(size_t)n * H_DIM + k] = f2b(W2[i]);
    } else if (i < 2 * H_DIM * H_DIM) {
        int j = i - H_DIM * H_DIM;
        int k = j >> 8, n = j & 255;
        Wt3[(size_t)n * H_DIM + k] = f2b(W3[j]);
    }
}

// ---------------- CSR build: scan, bases, scatter, finalize ----------------

__global__ __launch_bounds__(256) void scanH_kernel(unsigned int* __restrict__ Hg,
                                                    unsigned int* __restrict__ Btot) {
    __shared__ unsigned int tile[256];
    int b = blockIdx.x, t = threadIdx.x;
    unsigned int* row = Hg + (size_t)b * NCHUNK;
    int i0 = 2 * t, i1 = 2 * t + 1;
    unsigned int v0 = (i0 < NCHUNK) ? row[i0] : 0u;
    unsigned int v1 = (i1 < NCHUNK) ? row[i1] : 0u;
    unsigned int pair = v0 + v1;
    tile[t] = pair;
    __syncthreads();
    #pragma unroll
    for (int o = 1; o < 256; o <<= 1) {
        unsigned int add = (t >= o) ? tile[t - o] : 0u;
        __syncthreads();
        tile[t] += add;
        __syncthreads();
    }
    unsigned int excl = tile[t] - pair;
    if (i0 < NCHUNK) row[i0] = excl;
    if (i1 < NCHUNK) row[i1] = excl + v0;
    if (t == 255) Btot[b] = tile[255];
}

__global__ __launch_bounds__(256) void base_kernel(const unsigned int* __restrict__ Btot,
                                                   unsigned int* __restrict__ bucketBase,
                                                   const int* __restrict__ batch,
                                                   int* __restrict__ gstart,
                                                   int* __restrict__ rowptr,
                                                   float* __restrict__ pooled) {
    __shared__ unsigned int tile[256];
    int t = threadIdx.x;
    unsigned int v = (t < NBUCKET) ? Btot[t] : 0u;
    tile[t] = v;
    __syncthreads();
    #pragma unroll
    for (int o = 1; o < 256; o <<= 1) {
        unsigned int add = (t >= o) ? tile[t - o] : 0u;
        __syncthreads();
        tile[t] += add;
        __syncthreads();
    }
    if (t < NBUCKET) bucketBase[t] = tile[t] - v;
    if (t == NBUCKET - 1) bucketBase[NBUCKET] = tile[t];   // = N_EDGES
    if (t == 0) rowptr[N_NODES] = N_EDGES;
    if (t <= G_NUM) {
        int lo = 0, hi = N_NODES;
        while (lo < hi) {
            int mid = (lo + hi) >> 1;
            if (batch[mid] < t) lo = mid + 1; else hi = mid;
        }
        gstart[t] = lo;
    }
    for (int i = t; i < G_NUM * H_DIM; i += 256) pooled[i] = 0.f;
}

__global__ __launch_bounds__(512) void scatter_kernel(const int* __restrict__ src,
                                                      const int* __restrict__ dst,
                                                      const unsigned int* __restrict__ Hg,
                                                      const unsigned int* __restrict__ bucketBase,
                                                      unsigned int* __restrict__ tmp) {
    __shared__ unsigned int off[256];
    int blk = blockIdx.x, t = threadIdx.x;
    if (t < 256)
        off[t] = (t < NBUCKET) ? (bucketBase[t] + Hg[(size_t)t * NCHUNK + blk]) : 0u;
    __syncthreads();
    int base = blk * CHUNK;
    #pragma unroll
    for (int k = 0; k < 4; k++) {
        int i = base + k * 512 + t;
        if (i < N_EDGES) {
            int d = dst[i], s = src[i];
            unsigned int slot = atomicAdd(&off[d >> 8], 1u);
            tmp[slot] = ((unsigned int)(d & 255) << 16) | (unsigned int)s;
        }
    }
}

__global__ __launch_bounds__(256) void finalize_kernel(const unsigned int* __restrict__ tmp,
                                                       const unsigned int* __restrict__ bucketBase,
                                                       int* __restrict__ rowptr,
                                                       float* __restrict__ dinv,
                                                       unsigned short* __restrict__ csr_src) {
    __shared__ unsigned int te[K4CAP];
    __shared__ unsigned int h2[256];
    __shared__ unsigned int sc[256];
    __shared__ unsigned int off2[256];
    int b = blockIdx.x, t = threadIdx.x;
    unsigned int beg = bucketBase[b], end = bucketBase[b + 1];
    int cnt = (int)(end - beg);
    bool lds_ok = (cnt <= K4CAP);
    h2[t] = 0u;
    __syncthreads();
    for (int i = t; i < cnt; i += 256) {
        unsigned int u = tmp[beg + i];
        if (lds_ok) te[i] = u;
        atomicAdd(&h2[u >> 16], 1u);
    }
    __syncthreads();
    unsigned int c = h2[t];
    sc[t] = c;
    __syncthreads();
    #pragma unroll
    for (int o = 1; o < 256; o <<= 1) {
        unsigned int add = (t >= o) ? sc[t - o] : 0u;
        __syncthreads();
        sc[t] += add;
        __syncthreads();
    }
    unsigned int excl = sc[t] - c;
    int v = (b << 8) + t;
    if (v < N_NODES) {
        rowptr[v] = (int)(beg + excl);
        dinv[v] = rsqrtf((float)c + 1.0f);
    }
    off2[t] = excl;
    __syncthreads();
    for (int i = t; i < cnt; i += 256) {
        unsigned int u = lds_ok ? te[i] : tmp[beg + i];
        unsigned int lo = u >> 16;
        unsigned int s2 = atomicAdd(&off2[lo], 1u);
        csr_src[beg + s2] = (unsigned short)(u & 0xFFFFu);
    }
}

// ------- gemm body: bf16 MFMA, BN=256, fp8*dinv output (rows [bm, bm+128) ∩ [.., mend)) -------

__device__ __forceinline__ void gemm_body_f8(const unsigned short* __restrict__ A,
                                             const unsigned short* __restrict__ Bt,
                                             unsigned char* __restrict__ C8,
                                             const float* __restrict__ dinv,
                                             int M, int K, int bm) {
    __shared__ unsigned short As[128][SK];
    __shared__ unsigned short Bs[256][SK];
    int t = threadIdx.x;
    int wave = t >> 6, lane = t & 63;
    int wm0 = (wave & 1) * 64, wn0 = (wave >> 1) * 64;
    int l15 = lane & 15, lq = lane >> 4;
    float4v acc[4][4];
    #pragma unroll
    for (int i = 0; i < 4; i++)
        #pragma unroll
        for (int j = 0; j < 4; j++)
            acc[i][j] = (float4v){0.f, 0.f, 0.f, 0.f};

    for (int k0 = 0; k0 < K; k0 += 32) {
        {
            int row = t >> 2, koff = (t & 3) * 8;
            uint4 va = make_uint4(0u, 0u, 0u, 0u);
            if (bm + row < M)
                va = *(const uint4*)(A + (size_t)(bm + row) * K + k0 + koff);
            *(uint4*)&As[row][koff] = va;
        }
        #pragma unroll
        for (int h = 0; h < 2; h++) {
            int c = t + h * 512;
            int row = c >> 2, koff = (c & 3) * 8;
            uint4 vb = *(const uint4*)(Bt + (size_t)row * K + k0 + koff);
            *(uint4*)&Bs[row][koff] = vb;
        }
        __syncthreads();
        short8v af[4], bf[4];
        #pragma unroll
        for (int i = 0; i < 4; i++) {
            af[i] = *(const short8v*)&As[wm0 + i * 16 + l15][lq * 8];
            bf[i] = *(const short8v*)&Bs[wn0 + i * 16 + l15][lq * 8];
        }
        #pragma unroll
        for (int i = 0; i < 4; i++)
            #pragma unroll
            for (int j = 0; j < 4; j++)
                acc[i][j] = __builtin_amdgcn_mfma_f32_16x16x32_bf16(af[i], bf[j], acc[i][j], 0, 0, 0);
        __syncthreads();
    }
    #pragma unroll
    for (int i = 0; i < 4; i++) {
        #pragma unroll
        for (int r = 0; r < 4; r++) {
            int row = bm + wm0 + i * 16 + lq * 4 + r;
            if (row < M) {
                float dv = dinv[row];
                #pragma unroll
                for (int j = 0; j < 4; j++) {
                    int col = wn0 + j * 16 + l15;
                    C8[(size_t)row * H_DIM + col] = f2fp8(dv * acc[i][j][r]);
                }
            }
        }
    }
}

// ------- gather body (R7-verified): one node per 16-lane group, shfl id distribution,
//         8-deep load unroll, software-pipelined csr_src id fetch -------

template<bool W8>
__device__ __forceinline__ void gather_body(const unsigned char* __restrict__ xw,
                                            unsigned short* __restrict__ out,
                                            const int* __restrict__ rowptr,
                                            const unsigned short* __restrict__ csr_src,
                                            const float* __restrict__ dinv,
                                            const float* __restrict__ bias,
                                            const float* __restrict__ gamma,
                                            const float* __restrict__ beta,
                                            int node, int p, int gbase) {
    int beg = rowptr[node];
    int deg = rowptr[node + 1] - beg;
    float d = dinv[node];
    const unsigned char* xp = xw + (size_t)p * 16;

    float2v acc2[8];
    #pragma unroll
    for (int k = 0; k < 8; k++) acc2[k] = (float2v){0.f, 0.f};

    {   // self contribution
        uint4 v = *(const uint4*)(xp + (size_t)node * H_DIM);
        if constexpr (W8) accfma16(acc2, v, d);
        else              accadd16(acc2, v);
    }

    int sv = 0; float wv = 0.f;
    if (p < deg) {
        sv = (int)csr_src[beg + p];
        if constexpr (W8) wv = dinv[sv];
    }

    for (int b0 = 0; b0 < deg; b0 += 16) {
        int m = deg - b0; if (m > 16) m = 16;
        int sv_n = 0; float wv_n = 0.f;
        int rem = deg - b0 - 16;
        if (rem > 0 && p < rem) {
            sv_n = (int)csr_src[beg + b0 + 16 + p];
            if constexpr (W8) wv_n = dinv[sv_n];
        }
        int j = 0;
        for (; j + 8 <= m; j += 8) {
            int s0 = __shfl(sv, gbase | j, 64);
            int s1 = __shfl(sv, gbase | (j + 1), 64);
            int s2 = __shfl(sv, gbase | (j + 2), 64);
            int s3 = __shfl(sv, gbase | (j + 3), 64);
            int s4 = __shfl(sv, gbase | (j + 4), 64);
            int s5 = __shfl(sv, gbase | (j + 5), 64);
            int s6 = __shfl(sv, gbase | (j + 6), 64);
            int s7 = __shfl(sv, gbase | (j + 7), 64);
            uint4 v0 = *(const uint4*)(xp + (size_t)s0 * H_DIM);
            uint4 v1 = *(const uint4*)(xp + (size_t)s1 * H_DIM);
            uint4 v2 = *(const uint4*)(xp + (size_t)s2 * H_DIM);
            uint4 v3 = *(const uint4*)(xp + (size_t)s3 * H_DIM);
            uint4 v4 = *(const uint4*)(xp + (size_t)s4 * H_DIM);
            uint4 v5 = *(const uint4*)(xp + (size_t)s5 * H_DIM);
            uint4 v6 = *(const uint4*)(xp + (size_t)s6 * H_DIM);
            uint4 v7 = *(const uint4*)(xp + (size_t)s7 * H_DIM);
            if constexpr (W8) {
                float w0 = __shfl(wv, gbase | j, 64);
                float w1 = __shfl(wv, gbase | (j + 1), 64);
                float w2 = __shfl(wv, gbase | (j + 2), 64);
                float w3 = __shfl(wv, gbase | (j + 3), 64);
                float w4 = __shfl(wv, gbase | (j + 4), 64);
                float w5 = __shfl(wv, gbase | (j + 5), 64);
                float w6 = __shfl(wv, gbase | (j + 6), 64);
                float w7 = __shfl(wv, gbase | (j + 7), 64);
                accfma16(acc2, v0, w0); accfma16(acc2, v1, w1);
                accfma16(acc2, v2, w2); accfma16(acc2, v3, w3);
                accfma16(acc2, v4, w4); accfma16(acc2, v5, w5);
                accfma16(acc2, v6, w6); accfma16(acc2, v7, w7);
            } else {
                accadd16(acc2, v0); accadd16(acc2, v1);
                accadd16(acc2, v2); accadd16(acc2, v3);
                accadd16(acc2, v4); accadd16(acc2, v5);
                accadd16(acc2, v6); accadd16(acc2, v7);
            }
        }
        for (; j + 4 <= m; j += 4) {
            int s0 = __shfl(sv, gbase | j, 64);
            int s1 = __shfl(sv, gbase | (j + 1), 64);
            int s2 = __shfl(sv, gbase | (j + 2), 64);
            int s3 = __shfl(sv, gbase | (j + 3), 64);
            uint4 v0 = *(const uint4*)(xp + (size_t)s0 * H_DIM);
            uint4 v1 = *(const uint4*)(xp + (size_t)s1 * H_DIM);
            uint4 v2 = *(const uint4*)(xp + (size_t)s2 * H_DIM);
            uint4 v3 = *(const uint4*)(xp + (size_t)s3 * H_DIM);
            if constexpr (W8) {
                float w0 = __shfl(wv, gbase | j, 64);
                float w1 = __shfl(wv, gbase | (j + 1), 64);
                float w2 = __shfl(wv, gbase | (j + 2), 64);
                float w3 = __shfl(wv, gbase | (j + 3), 64);
                accfma16(acc2, v0, w0); accfma16(acc2, v1, w1);
                accfma16(acc2, v2, w2); accfma16(acc2, v3, w3);
            } else {
                accadd16(acc2, v0); accadd16(acc2, v1);
                accadd16(acc2, v2); accadd16(acc2, v3);
            }
        }
        for (; j < m; ++j) {
            int s0 = __shfl(sv, gbase | j, 64);
            uint4 v0 = *(const uint4*)(xp + (size_t)s0 * H_DIM);
            if constexpr (W8) {
                float w0 = __shfl(wv, gbase | j, 64);
                accfma16(acc2, v0, w0);
            } else {
                accadd16(acc2, v0);
            }
        }
        sv = sv_n; wv = wv_n;
    }

    float v[16];
    #pragma unroll
    for (int k = 0; k < 8; k++) { v[2 * k] = d * acc2[k].x; v[2 * k + 1] = d * acc2[k].y; }

    #pragma unroll
    for (int q = 0; q < 4; q++) {
        float4 bi = ((const float4*)bias)[p * 4 + q];
        v[q * 4 + 0] += bi.x; v[q * 4 + 1] += bi.y;
        v[q * 4 + 2] += bi.z; v[q * 4 + 3] += bi.w;
    }
    float s = 0.f, ss = 0.f;
    #pragma unroll
    for (int k = 0; k < 16; k++) { s += v[k]; ss += v[k] * v[k]; }
    #pragma unroll
    for (int o = 1; o < 16; o <<= 1) {
        s  += __shfl_xor(s, o, 64);
        ss += __shfl_xor(ss, o, 64);
    }
    float mn = s * (1.f / H_DIM);
    float var = ss * (1.f / H_DIM) - mn * mn;
    float rstd = rsqrtf(var + 1e-5f);
    #pragma unroll
    for (int q = 0; q < 4; q++) {
        float4 ga = ((const float4*)gamma)[p * 4 + q];
        float4 be = ((const float4*)beta)[p * 4 + q];
        v[q * 4 + 0] = fmaxf((v[q * 4 + 0] - mn) * rstd * ga.x + be.x, 0.f);
        v[q * 4 + 1] = fmaxf((v[q * 4 + 1] - mn) * rstd * ga.y + be.y, 0.f);
        v[q * 4 + 2] = fmaxf((v[q * 4 + 2] - mn) * rstd * ga.z + be.z, 0.f);
        v[q * 4 + 3] = fmaxf((v[q * 4 + 3] - mn) * rstd * ga.w + be.w, 0.f);
    }

    unsigned short* op = out + (size_t)node * H_DIM + p * 16;
    uint4 o0, o1;
    o0.x = pack2(v[0], v[1]);   o0.y = pack2(v[2], v[3]);
    o0.z = pack2(v[4], v[5]);   o0.w = pack2(v[6], v[7]);
    o1.x = pack2(v[8], v[9]);   o1.y = pack2(v[10], v[11]);
    o1.z = pack2(v[12], v[13]); o1.w = pack2(v[14], v[15]);
    *(uint4*)op = o0;
    *(uint4*)(op + 8) = o1;
}

// ------- gg: fused [gather quarter (blocks < GBk)] + [gemm quarter (rest)] -------
// gemm quarter mstart depends on PREVIOUS dispatch's gather quarter (row-aligned);
// gather reads Pin (all rows), gemm writes Pout (different buffer) -> no race.

template<bool W8>
__global__ __launch_bounds__(512) void gg_kernel(int GBk, int nstart, int nend,
                                                 const unsigned char* __restrict__ Pin,
                                                 unsigned short* __restrict__ Hb,
                                                 int mstart, int mend,
                                                 const unsigned short* __restrict__ Wt,
                                                 unsigned char* __restrict__ Pout,
                                                 const int* __restrict__ rowptr,
                                                 const unsigned short* __restrict__ csr_src,
                                                 const float* __restrict__ dinv,
                                                 const float* __restrict__ bias,
                                                 const float* __restrict__ gamma,
                                                 const float* __restrict__ beta) {
    int b = blockIdx.x;
    if (b < GBk) {
        int lane = threadIdx.x & 63, wave = threadIdx.x >> 6;
        int node = nstart + b * 32 + wave * 4 + (lane >> 4);   // 32 nodes / 512-thr block
        if (node >= nend) return;
        gather_body<W8>(Pin, Hb, rowptr, csr_src, dinv, bias, gamma, beta,
                        node, lane & 15, lane & 48);
        return;
    }
    gemm_body_f8(Hb, Wt, Pout, dinv, mend, H_DIM, mstart + (b - GBk) * 128);
}

// ---------------- pooling (uint loads: 2 bf16/lane) ----------------

__global__ __launch_bounds__(128) void pool_kernel(const unsigned int* __restrict__ h32,
                                                   const int* __restrict__ batch,
                                                   float* __restrict__ pooled, int n) {
    int t = threadIdx.x;
    int start = blockIdx.x * 64;
    int end = min(start + 64, n);
    if (start >= n) return;
    int cur = batch[start];
    float a0 = 0.f, a1 = 0.f;
    for (int i = start; i < end; ++i) {
        int g = batch[i];
        if (g != cur) {
            atomicAdd(&pooled[(size_t)cur * H_DIM + 2 * t], a0);
            atomicAdd(&pooled[(size_t)cur * H_DIM + 2 * t + 1], a1);
            a0 = a1 = 0.f;
            cur = g;
        }
        unsigned int u = h32[(size_t)i * (H_DIM / 2) + t];
        a0 += b2f((unsigned short)(u & 0xffffu));
        a1 += b2f((unsigned short)(u >> 16));
    }
    atomicAdd(&pooled[(size_t)cur * H_DIM + 2 * t], a0);
    atomicAdd(&pooled[(size_t)cur * H_DIM + 2 * t + 1], a1);
}

// ---------------- FC head ----------------

__global__ __launch_bounds__(256) void fc_kernel(const float* __restrict__ pooled,
                                                 const int* __restrict__ gstart,
                                                 const float* __restrict__ gattr,
                                                 const float* __restrict__ fcW1,
                                                 const float* __restrict__ fcb1,
                                                 const float* __restrict__ fcW2,
                                                 const float* __restrict__ fcb2,
                                                 float* __restrict__ out) {
    __shared__ float zc[H_DIM + A_DIM];
    __shared__ float z1[H_DIM];
    int g = blockIdx.x, t = threadIdx.x;
    int c_i = gstart[g + 1] - gstart[g];
    float c = (float)(c_i > 1 ? c_i : 1);
    zc[t] = pooled[(size_t)g * H_DIM + t] / c;
    if (t < A_DIM) zc[H_DIM + t] = gattr[g * A_DIM + t];
    __syncthreads();
    float s = fcb1[t];
    for (int k = 0; k < H_DIM + A_DIM; k++)
        s += zc[k] * fcW1[(size_t)k * H_DIM + t];
    z1[t] = fmaxf(s, 0.f) * fcW2[t];
    __syncthreads();
    for (int off = 128; off; off >>= 1) {
        if (t < off) z1[t] += z1[t + off];
        __syncthreads();
    }
    if (t == 0) out[g] = z1[0] + fcb2[0];
}

// ---------------- launch ----------------

extern "C" void kernel_launch(void* const* d_in, const int* in_sizes, int n_in,
                              void* d_out, int out_size, void* d_ws, size_t ws_size,
                              hipStream_t stream) {
    const float* x     = (const float*)d_in[0];
    const float* gattr = (const float*)d_in[1];
    const int*   ei    = (const int*)d_in[2];
    const int*   batch = (const int*)d_in[3];
    const float* W1 = (const float*)d_in[4];  const float* b1 = (const float*)d_in[5];
    const float* W2 = (const float*)d_in[6];  const float* b2 = (const float*)d_in[7];
    const float* W3 = (const float*)d_in[8];  const float* b3 = (const float*)d_in[9];
    const float* g1 = (const float*)d_in[10]; const float* be1 = (const float*)d_in[11];
    const float* g2 = (const float*)d_in[12]; const float* be2 = (const float*)d_in[13];
    const float* g3 = (const float*)d_in[14]; const float* be3 = (const float*)d_in[15];
    const float* fcW1 = (const float*)d_in[16]; const float* fcb1 = (const float*)d_in[17];
    const float* fcW2 = (const float*)d_in[18]; const float* fcb2 = (const float*)d_in[19];
    float* out = (float*)d_out;

    char* w = (char*)d_ws;
    unsigned char*  Pb8  = (unsigned char*)w; w += (size_t)N_NODES * H_DIM;       // P1 / P3 fp8
    unsigned char*  Pb8b = (unsigned char*)w; w += (size_t)N_NODES * H_DIM;       // P2 fp8
    unsigned short* Hb   = (unsigned short*)w; w += (size_t)N_NODES * H_DIM * 2;  // h bf16
    unsigned short* Wt2 = (unsigned short*)w; w += (size_t)H_DIM * H_DIM * 2;
    unsigned short* Wt3 = (unsigned short*)w; w += (size_t)H_DIM * H_DIM * 2;
    float* dinv   = (float*)w; w += (size_t)N_NODES * 4;
    float* pooled = (float*)w; w += (size_t)G_NUM * H_DIM * 4;
    int* rowptr   = (int*)w;   w += (size_t)(N_NODES + 4) * 4;
    unsigned int* Hg = (unsigned int*)w;      w += (size_t)256 * NCHUNK * 4;
    unsigned int* Btot = (unsigned int*)w;    w += (size_t)256 * 4;
    unsigned int* bucketBase = (unsigned int*)w; w += (size_t)(NBUCKET + 4) * 4;
    unsigned int* tmp = (unsigned int*)w;     w += (size_t)N_EDGES * 4;
    unsigned short* csr_src = (unsigned short*)w; w += (size_t)N_EDGES * 2;
    int* gstart   = (int*)w;   w += (size_t)(G_NUM + 1) * 4;

    const int* srcp = ei;
    const int* dstp = ei + N_EDGES;

    // ---- fuse0: bucket count + GEMM1 (X*W1 -> fp8 unscaled) + W transposes ----
    {
        const int CB = NCHUNK;                          // 391
        const int GB = (N_NODES + 127) / 128;           // 391
        const int WB = (2 * H_DIM * H_DIM + 511) / 512; // 256
        fuse0_kernel<<<CB + GB + WB, 512, 0, stream>>>(dstp, Hg, x, W1, Pb8, W2, Wt2, W3, Wt3);
    }
    // ---- CSR build ----
    scanH_kernel<<<NBUCKET, 256, 0, stream>>>(Hg, Btot);
    base_kernel<<<1, 256, 0, stream>>>(Btot, bucketBase, batch, gstart, rowptr, pooled);
    scatter_kernel<<<NCHUNK, 512, 0, stream>>>(srcp, dstp, Hg, bucketBase, tmp);
    finalize_kernel<<<NBUCKET, 256, 0, stream>>>(tmp, bucketBase, rowptr, dinv, csr_src);

    const int GQB = (QN + 31) / 32;     // 391 gather blocks per quarter
    const int MQB = (QN + 127) / 128;   // 98 gemm blocks per quarter

    // ---- pair 1: G1 (weighted, Pb8->Hb) quarter-pipelined with M2 (Hb->Pb8b) ----
    for (int q = 0; q < 5; ++q) {
        int GBk = (q < 4) ? GQB : 0;
        int MBk = (q > 0) ? MQB : 0;
        int ns = q * QN, ms = (q - 1) * QN;
        gg_kernel<true><<<GBk + MBk, 512, 0, stream>>>(GBk, ns, ns + QN, Pb8, Hb,
                                                       ms, ms + QN, Wt2, Pb8b,
                                                       rowptr, csr_src, dinv, b1, g1, be1);
    }
    // ---- pair 2: G2 (Pb8b->Hb) quarter-pipelined with M3 (Hb->Pb8) ----
    for (int q = 0; q < 5; ++q) {
        int GBk = (q < 4) ? GQB : 0;
        int MBk = (q > 0) ? MQB : 0;
        int ns = q * QN, ms = (q - 1) * QN;
        gg_kernel<false><<<GBk + MBk, 512, 0, stream>>>(GBk, ns, ns + QN, Pb8b, Hb,
                                                        ms, ms + QN, Wt3, Pb8,
                                                        rowptr, csr_src, dinv, b2, g2, be2);
    }
    // ---- layer 3 gather (Pb8->Hb, full) ----
    {
        const int GBk = (N_NODES + 31) / 32;    // 1563
        gg_kernel<false><<<GBk, 512, 0, stream>>>(GBk, 0, N_NODES, Pb8, Hb,
                                                  0, 0, Wt3, Pb8b,
                                                  rowptr, csr_src, dinv, b3, g3, be3);
    }
    // ---- pool + FC head ----
    pool_kernel<<<(N_NODES + 63) / 64, 128, 0, stream>>>((const unsigned int*)Hb, batch, pooled, N_NODES);
    fc_kernel<<<G_NUM, 256, 0, stream>>>(pooled, gstart, gattr, fcW1, fcb1, fcW2, fcb2, out);
}

// Round 11
// 317.000 us; speedup vs baseline: 1.2624x; 1.2624x over previous
//
#include <hip/hip_runtime.h>
#include <hip/hip_bf16.h>

#define N_NODES 50000
#define N_EDGES 800000
#define F_IN    128
#define H_DIM   256
#define G_NUM   64
#define A_DIM   8

#define NBUCKET 196                 // dst>>8, dst<50000
#define NCHUNK  391                 // ceil(800000/2048)
#define CHUNK   2048
#define K4CAP   6144                // bucket edge capacity in LDS

typedef __attribute__((ext_vector_type(8))) short short8v;
typedef __attribute__((ext_vector_type(4))) float float4v;
typedef __attribute__((ext_vector_type(2))) float float2v;

__device__ __forceinline__ float b2f(unsigned short u) {
    return __uint_as_float(((unsigned int)u) << 16);
}
__device__ __forceinline__ unsigned short f2b(float v) {
    return __hip_bfloat16_raw(__float2bfloat16(v)).x;
}
__device__ __forceinline__ unsigned char f2fp8(float v) {
    return (unsigned char)(__builtin_amdgcn_cvt_pk_fp8_f32(v, v, 0, false) & 0xff);
}
__device__ __forceinline__ unsigned int pack2(float a, float b) {
    return (unsigned int)f2b(a) | ((unsigned int)f2b(b) << 16);
}
// 16 fp8 -> 8 v_pk_add_f32 (inputs pre-scaled by dinv[src])
__device__ __forceinline__ void accadd16(float2v* a, uint4 v) {
    a[0] += __builtin_amdgcn_cvt_pk_f32_fp8((int)v.x, false);
    a[1] += __builtin_amdgcn_cvt_pk_f32_fp8((int)v.x, true);
    a[2] += __builtin_amdgcn_cvt_pk_f32_fp8((int)v.y, false);
    a[3] += __builtin_amdgcn_cvt_pk_f32_fp8((int)v.y, true);
    a[4] += __builtin_amdgcn_cvt_pk_f32_fp8((int)v.z, false);
    a[5] += __builtin_amdgcn_cvt_pk_f32_fp8((int)v.z, true);
    a[6] += __builtin_amdgcn_cvt_pk_f32_fp8((int)v.w, false);
    a[7] += __builtin_amdgcn_cvt_pk_f32_fp8((int)v.w, true);
}
// 16 fp8 -> 8 v_pk_fma_f32 with scalar weight (unscaled input path)
__device__ __forceinline__ void accfma16(float2v* a, uint4 v, float w) {
    float2v w2 = {w, w};
    a[0] = __builtin_amdgcn_cvt_pk_f32_fp8((int)v.x, false) * w2 + a[0];
    a[1] = __builtin_amdgcn_cvt_pk_f32_fp8((int)v.x, true)  * w2 + a[1];
    a[2] = __builtin_amdgcn_cvt_pk_f32_fp8((int)v.y, false) * w2 + a[2];
    a[3] = __builtin_amdgcn_cvt_pk_f32_fp8((int)v.y, true)  * w2 + a[3];
    a[4] = __builtin_amdgcn_cvt_pk_f32_fp8((int)v.z, false) * w2 + a[4];
    a[5] = __builtin_amdgcn_cvt_pk_f32_fp8((int)v.z, true)  * w2 + a[5];
    a[6] = __builtin_amdgcn_cvt_pk_f32_fp8((int)v.w, false) * w2 + a[6];
    a[7] = __builtin_amdgcn_cvt_pk_f32_fp8((int)v.w, true)  * w2 + a[7];
}

#define SK 40

// ---------------- fuse0: [bucket count (LDS hist)] + [GEMM1 X(f32)*W1(f32) -> P fp8 unscaled]
//                  + [Wt2/Wt3 transposes] -- all dependency-free, zero global atomics --------

__global__ __launch_bounds__(512) void fuse0_kernel(const int* __restrict__ dst,
                                                    unsigned int* __restrict__ Hg,
                                                    const float* __restrict__ x,
                                                    const float* __restrict__ W1,
                                                    unsigned char* __restrict__ P8,
                                                    const float* __restrict__ W2,
                                                    unsigned short* __restrict__ Wt2,
                                                    const float* __restrict__ W3,
                                                    unsigned short* __restrict__ Wt3) {
    const int CB = NCHUNK;                 // 391 count blocks
    const int GB = (N_NODES + 127) / 128;  // 391 gemm blocks
    int b = blockIdx.x, t = threadIdx.x;
    if (b < CB) {
        __shared__ unsigned int h[256];
        if (t < 256) h[t] = 0u;
        __syncthreads();
        int base = b * CHUNK;
        #pragma unroll
        for (int k = 0; k < 4; k++) {
            int i = base + k * 512 + t;
            if (i < N_EDGES) atomicAdd(&h[dst[i] >> 8], 1u);
        }
        __syncthreads();
        if (t < 256) Hg[(size_t)t * NCHUNK + b] = h[t];
        return;
    }
    b -= CB;
    if (b < GB) {
        __shared__ unsigned short As[128][SK];
        __shared__ unsigned short Bs[256][SK];
        int wave = t >> 6, lane = t & 63;
        int wm0 = (wave & 1) * 64, wn0 = (wave >> 1) * 64;
        int bm = b * 128;
        int l15 = lane & 15, lq = lane >> 4;
        float4v acc[4][4];
        #pragma unroll
        for (int i = 0; i < 4; i++)
            #pragma unroll
            for (int j = 0; j < 4; j++)
                acc[i][j] = (float4v){0.f, 0.f, 0.f, 0.f};

        for (int k0 = 0; k0 < F_IN; k0 += 32) {
            {
                int row = t >> 2, koff = (t & 3) * 8;
                short8v tmp = (short8v){0,0,0,0,0,0,0,0};
                if (bm + row < N_NODES) {
                    const float* xp = x + (size_t)(bm + row) * F_IN + k0 + koff;
                    float4 a0 = *(const float4*)xp;
                    float4 a1 = *(const float4*)(xp + 4);
                    tmp[0] = (short)f2b(a0.x); tmp[1] = (short)f2b(a0.y);
                    tmp[2] = (short)f2b(a0.z); tmp[3] = (short)f2b(a0.w);
                    tmp[4] = (short)f2b(a1.x); tmp[5] = (short)f2b(a1.y);
                    tmp[6] = (short)f2b(a1.z); tmp[7] = (short)f2b(a1.w);
                }
                *(short8v*)&As[row][koff] = tmp;
            }
            #pragma unroll
            for (int h = 0; h < 2; h++) {
                int c = t + h * 512;
                int n = c >> 2, koff = (c & 3) * 8;
                short8v tmp;
                #pragma unroll
                for (int kk = 0; kk < 8; kk++)
                    tmp[kk] = (short)f2b(W1[(size_t)(k0 + koff + kk) * H_DIM + n]);
                *(short8v*)&Bs[n][koff] = tmp;
            }
            __syncthreads();
            short8v af[4], bf[4];
            #pragma unroll
            for (int i = 0; i < 4; i++) {
                af[i] = *(const short8v*)&As[wm0 + i * 16 + l15][lq * 8];
                bf[i] = *(const short8v*)&Bs[wn0 + i * 16 + l15][lq * 8];
            }
            #pragma unroll
            for (int i = 0; i < 4; i++)
                #pragma unroll
                for (int j = 0; j < 4; j++)
                    acc[i][j] = __builtin_amdgcn_mfma_f32_16x16x32_bf16(af[i], bf[j], acc[i][j], 0, 0, 0);
            __syncthreads();
        }
        #pragma unroll
        for (int i = 0; i < 4; i++) {
            #pragma unroll
            for (int r = 0; r < 4; r++) {
                int row = bm + wm0 + i * 16 + lq * 4 + r;
                if (row < N_NODES) {
                    #pragma unroll
                    for (int j = 0; j < 4; j++) {
                        int col = wn0 + j * 16 + l15;
                        P8[(size_t)row * H_DIM + col] = f2fp8(acc[i][j][r]);
                    }
                }
            }
        }
        return;
    }
    b -= GB;
    int i = b * 512 + t;
    if (i < H_DIM * H_DIM) {
        int k = i >> 8, n = i & 255;
        Wt2[(size_t)n * H_DIM + k] = f2b(W2[i]);
    } else if (i < 2 * H_DIM * H_DIM) {
        int j = i - H_DIM * H_DIM;
        int k = j >> 8, n = j & 255;
        Wt3[(size_t)n * H_DIM + k] = f2b(W3[j]);
    }
}

// ---------------- CSR build: scan, bases, scatter, finalize ----------------

__global__ __launch_bounds__(256) void scanH_kernel(unsigned int* __restrict__ Hg,
                                                    unsigned int* __restrict__ Btot) {
    __shared__ unsigned int tile[256];
    int b = blockIdx.x, t = threadIdx.x;
    unsigned int* row = Hg + (size_t)b * NCHUNK;
    int i0 = 2 * t, i1 = 2 * t + 1;
    unsigned int v0 = (i0 < NCHUNK) ? row[i0] : 0u;
    unsigned int v1 = (i1 < NCHUNK) ? row[i1] : 0u;
    unsigned int pair = v0 + v1;
    tile[t] = pair;
    __syncthreads();
    #pragma unroll
    for (int o = 1; o < 256; o <<= 1) {
        unsigned int add = (t >= o) ? tile[t - o] : 0u;
        __syncthreads();
        tile[t] += add;
        __syncthreads();
    }
    unsigned int excl = tile[t] - pair;
    if (i0 < NCHUNK) row[i0] = excl;
    if (i1 < NCHUNK) row[i1] = excl + v0;
    if (t == 255) Btot[b] = tile[255];
}

__global__ __launch_bounds__(256) void base_kernel(const unsigned int* __restrict__ Btot,
                                                   unsigned int* __restrict__ bucketBase,
                                                   const int* __restrict__ batch,
                                                   int* __restrict__ gstart,
                                                   int* __restrict__ rowptr,
                                                   float* __restrict__ pooled) {
    __shared__ unsigned int tile[256];
    int t = threadIdx.x;
    unsigned int v = (t < NBUCKET) ? Btot[t] : 0u;
    tile[t] = v;
    __syncthreads();
    #pragma unroll
    for (int o = 1; o < 256; o <<= 1) {
        unsigned int add = (t >= o) ? tile[t - o] : 0u;
        __syncthreads();
        tile[t] += add;
        __syncthreads();
    }
    if (t < NBUCKET) bucketBase[t] = tile[t] - v;
    if (t == NBUCKET - 1) bucketBase[NBUCKET] = tile[t];   // = N_EDGES
    if (t == 0) rowptr[N_NODES] = N_EDGES;
    if (t <= G_NUM) {
        int lo = 0, hi = N_NODES;
        while (lo < hi) {
            int mid = (lo + hi) >> 1;
            if (batch[mid] < t) lo = mid + 1; else hi = mid;
        }
        gstart[t] = lo;
    }
    for (int i = t; i < G_NUM * H_DIM; i += 256) pooled[i] = 0.f;
}

__global__ __launch_bounds__(512) void scatter_kernel(const int* __restrict__ src,
                                                      const int* __restrict__ dst,
                                                      const unsigned int* __restrict__ Hg,
                                                      const unsigned int* __restrict__ bucketBase,
                                                      unsigned int* __restrict__ tmp) {
    __shared__ unsigned int off[256];
    int blk = blockIdx.x, t = threadIdx.x;
    if (t < 256)
        off[t] = (t < NBUCKET) ? (bucketBase[t] + Hg[(size_t)t * NCHUNK + blk]) : 0u;
    __syncthreads();
    int base = blk * CHUNK;
    #pragma unroll
    for (int k = 0; k < 4; k++) {
        int i = base + k * 512 + t;
        if (i < N_EDGES) {
            int d = dst[i], s = src[i];
            unsigned int slot = atomicAdd(&off[d >> 8], 1u);
            tmp[slot] = ((unsigned int)(d & 255) << 16) | (unsigned int)s;
        }
    }
}

__global__ __launch_bounds__(256) void finalize_kernel(const unsigned int* __restrict__ tmp,
                                                       const unsigned int* __restrict__ bucketBase,
                                                       int* __restrict__ rowptr,
                                                       float* __restrict__ dinv,
                                                       unsigned short* __restrict__ csr_src) {
    __shared__ unsigned int te[K4CAP];
    __shared__ unsigned int h2[256];
    __shared__ unsigned int sc[256];
    __shared__ unsigned int off2[256];
    int b = blockIdx.x, t = threadIdx.x;
    unsigned int beg = bucketBase[b], end = bucketBase[b + 1];
    int cnt = (int)(end - beg);
    bool lds_ok = (cnt <= K4CAP);
    h2[t] = 0u;
    __syncthreads();
    for (int i = t; i < cnt; i += 256) {
        unsigned int u = tmp[beg + i];
        if (lds_ok) te[i] = u;
        atomicAdd(&h2[u >> 16], 1u);
    }
    __syncthreads();
    unsigned int c = h2[t];
    sc[t] = c;
    __syncthreads();
    #pragma unroll
    for (int o = 1; o < 256; o <<= 1) {
        unsigned int add = (t >= o) ? sc[t - o] : 0u;
        __syncthreads();
        sc[t] += add;
        __syncthreads();
    }
    unsigned int excl = sc[t] - c;
    int v = (b << 8) + t;
    if (v < N_NODES) {
        rowptr[v] = (int)(beg + excl);
        dinv[v] = rsqrtf((float)c + 1.0f);
    }
    off2[t] = excl;
    __syncthreads();
    for (int i = t; i < cnt; i += 256) {
        unsigned int u = lds_ok ? te[i] : tmp[beg + i];
        unsigned int lo = u >> 16;
        unsigned int s2 = atomicAdd(&off2[lo], 1u);
        csr_src[beg + s2] = (unsigned short)(u & 0xFFFFu);
    }
}

// ------- bf16 MFMA GEMM, BN=256, fp8*dinv output (layers 2,3; pre-scaled for gather) -------

__global__ __launch_bounds__(512) void gemm_f8(const unsigned short* __restrict__ A,
                                               const unsigned short* __restrict__ Bt,
                                               unsigned char* __restrict__ C8,
                                               const float* __restrict__ dinv,
                                               int M, int K) {
    __shared__ unsigned short As[128][SK];
    __shared__ unsigned short Bs[256][SK];
    int t = threadIdx.x;
    int wave = t >> 6, lane = t & 63;
    int wm0 = (wave & 1) * 64, wn0 = (wave >> 1) * 64;
    int bm = blockIdx.x * 128;
    int l15 = lane & 15, lq = lane >> 4;
    float4v acc[4][4];
    #pragma unroll
    for (int i = 0; i < 4; i++)
        #pragma unroll
        for (int j = 0; j < 4; j++)
            acc[i][j] = (float4v){0.f, 0.f, 0.f, 0.f};

    for (int k0 = 0; k0 < K; k0 += 32) {
        {
            int row = t >> 2, koff = (t & 3) * 8;
            uint4 va = make_uint4(0u, 0u, 0u, 0u);
            if (bm + row < M)
                va = *(const uint4*)(A + (size_t)(bm + row) * K + k0 + koff);
            *(uint4*)&As[row][koff] = va;
        }
        #pragma unroll
        for (int h = 0; h < 2; h++) {
            int c = t + h * 512;
            int row = c >> 2, koff = (c & 3) * 8;
            uint4 vb = *(const uint4*)(Bt + (size_t)row * K + k0 + koff);
            *(uint4*)&Bs[row][koff] = vb;
        }
        __syncthreads();
        short8v af[4], bf[4];
        #pragma unroll
        for (int i = 0; i < 4; i++) {
            af[i] = *(const short8v*)&As[wm0 + i * 16 + l15][lq * 8];
            bf[i] = *(const short8v*)&Bs[wn0 + i * 16 + l15][lq * 8];
        }
        #pragma unroll
        for (int i = 0; i < 4; i++)
            #pragma unroll
            for (int j = 0; j < 4; j++)
                acc[i][j] = __builtin_amdgcn_mfma_f32_16x16x32_bf16(af[i], bf[j], acc[i][j], 0, 0, 0);
        __syncthreads();
    }
    #pragma unroll
    for (int i = 0; i < 4; i++) {
        #pragma unroll
        for (int r = 0; r < 4; r++) {
            int row = bm + wm0 + i * 16 + lq * 4 + r;
            if (row < M) {
                float dv = dinv[row];
                #pragma unroll
                for (int j = 0; j < 4; j++) {
                    int col = wn0 + j * 16 + l15;
                    C8[(size_t)row * H_DIM + col] = f2fp8(dv * acc[i][j][r]);
                }
            }
        }
    }
}

// -------- fp8 gather, 4 nodes per wave (one node per 16-lane group) -- R7-verified loop --------
// W8=false: inputs pre-scaled by dinv[src]; W8=true: unscaled inputs, weight dinv[s] per edge.
// POOL: instead of writing Hb, transpose block's 16 LN rows through LDS and accumulate
// into pooled via ~1 column-parallel atomicAdd per thread (no LDS atomics).

template<bool W8, bool POOL>
__global__ __launch_bounds__(256) void gather_ns(const unsigned char* __restrict__ xw,
                                                 unsigned short* __restrict__ out,
                                                 const int* __restrict__ rowptr,
                                                 const unsigned short* __restrict__ csr_src,
                                                 const float* __restrict__ dinv,
                                                 const float* __restrict__ bias,
                                                 const float* __restrict__ gamma,
                                                 const float* __restrict__ beta,
                                                 const int* __restrict__ batch,
                                                 float* __restrict__ pooled) {
    __shared__ float sh[POOL ? 16 * 260 : 4];
    __shared__ int gid_s[POOL ? 16 : 4];
    int lane = threadIdx.x & 63;
    int wave = threadIdx.x >> 6;
    int p = lane & 15;
    int gbase = lane & 48;
    int nl = wave * 4 + (lane >> 4);                     // node-local 0..15
    int node = blockIdx.x * 16 + nl;                     // N_NODES % 16 == 0
    int beg = rowptr[node];
    int deg = rowptr[node + 1] - beg;
    float d = dinv[node];
    const unsigned char* xp = xw + (size_t)p * 16;

    float2v acc2[8];
    #pragma unroll
    for (int k = 0; k < 8; k++) acc2[k] = (float2v){0.f, 0.f};

    // self contribution
    {
        uint4 v = *(const uint4*)(xp + (size_t)node * H_DIM);
        if constexpr (W8) accfma16(acc2, v, d);
        else              accadd16(acc2, v);
    }

    // pipelined id fetch for block 0
    int sv = 0; float wv = 0.f;
    if (p < deg) {
        sv = (int)csr_src[beg + p];
        if constexpr (W8) wv = dinv[sv];
    }

    for (int b0 = 0; b0 < deg; b0 += 16) {
        int m = deg - b0; if (m > 16) m = 16;
        int sv_n = 0; float wv_n = 0.f;
        int rem = deg - b0 - 16;
        if (rem > 0 && p < rem) {
            sv_n = (int)csr_src[beg + b0 + 16 + p];
            if constexpr (W8) wv_n = dinv[sv_n];
        }
        int j = 0;
        for (; j + 8 <= m; j += 8) {
            int s0 = __shfl(sv, gbase | j, 64);
            int s1 = __shfl(sv, gbase | (j + 1), 64);
            int s2 = __shfl(sv, gbase | (j + 2), 64);
            int s3 = __shfl(sv, gbase | (j + 3), 64);
            int s4 = __shfl(sv, gbase | (j + 4), 64);
            int s5 = __shfl(sv, gbase | (j + 5), 64);
            int s6 = __shfl(sv, gbase | (j + 6), 64);
            int s7 = __shfl(sv, gbase | (j + 7), 64);
            uint4 v0 = *(const uint4*)(xp + (size_t)s0 * H_DIM);
            uint4 v1 = *(const uint4*)(xp + (size_t)s1 * H_DIM);
            uint4 v2 = *(const uint4*)(xp + (size_t)s2 * H_DIM);
            uint4 v3 = *(const uint4*)(xp + (size_t)s3 * H_DIM);
            uint4 v4 = *(const uint4*)(xp + (size_t)s4 * H_DIM);
            uint4 v5 = *(const uint4*)(xp + (size_t)s5 * H_DIM);
            uint4 v6 = *(const uint4*)(xp + (size_t)s6 * H_DIM);
            uint4 v7 = *(const uint4*)(xp + (size_t)s7 * H_DIM);
            if constexpr (W8) {
                float w0 = __shfl(wv, gbase | j, 64);
                float w1 = __shfl(wv, gbase | (j + 1), 64);
                float w2 = __shfl(wv, gbase | (j + 2), 64);
                float w3 = __shfl(wv, gbase | (j + 3), 64);
                float w4 = __shfl(wv, gbase | (j + 4), 64);
                float w5 = __shfl(wv, gbase | (j + 5), 64);
                float w6 = __shfl(wv, gbase | (j + 6), 64);
                float w7 = __shfl(wv, gbase | (j + 7), 64);
                accfma16(acc2, v0, w0); accfma16(acc2, v1, w1);
                accfma16(acc2, v2, w2); accfma16(acc2, v3, w3);
                accfma16(acc2, v4, w4); accfma16(acc2, v5, w5);
                accfma16(acc2, v6, w6); accfma16(acc2, v7, w7);
            } else {
                accadd16(acc2, v0); accadd16(acc2, v1);
                accadd16(acc2, v2); accadd16(acc2, v3);
                accadd16(acc2, v4); accadd16(acc2, v5);
                accadd16(acc2, v6); accadd16(acc2, v7);
            }
        }
        for (; j + 4 <= m; j += 4) {
            int s0 = __shfl(sv, gbase | j, 64);
            int s1 = __shfl(sv, gbase | (j + 1), 64);
            int s2 = __shfl(sv, gbase | (j + 2), 64);
            int s3 = __shfl(sv, gbase | (j + 3), 64);
            uint4 v0 = *(const uint4*)(xp + (size_t)s0 * H_DIM);
            uint4 v1 = *(const uint4*)(xp + (size_t)s1 * H_DIM);
            uint4 v2 = *(const uint4*)(xp + (size_t)s2 * H_DIM);
            uint4 v3 = *(const uint4*)(xp + (size_t)s3 * H_DIM);
            if constexpr (W8) {
                float w0 = __shfl(wv, gbase | j, 64);
                float w1 = __shfl(wv, gbase | (j + 1), 64);
                float w2 = __shfl(wv, gbase | (j + 2), 64);
                float w3 = __shfl(wv, gbase | (j + 3), 64);
                accfma16(acc2, v0, w0); accfma16(acc2, v1, w1);
                accfma16(acc2, v2, w2); accfma16(acc2, v3, w3);
            } else {
                accadd16(acc2, v0); accadd16(acc2, v1);
                accadd16(acc2, v2); accadd16(acc2, v3);
            }
        }
        for (; j < m; ++j) {
            int s0 = __shfl(sv, gbase | j, 64);
            uint4 v0 = *(const uint4*)(xp + (size_t)s0 * H_DIM);
            if constexpr (W8) {
                float w0 = __shfl(wv, gbase | j, 64);
                accfma16(acc2, v0, w0);
            } else {
                accadd16(acc2, v0);
            }
        }
        sv = sv_n; wv = wv_n;
    }

    float v[16];
    #pragma unroll
    for (int k = 0; k < 8; k++) { v[2 * k] = d * acc2[k].x; v[2 * k + 1] = d * acc2[k].y; }

    // bias + LN + ReLU
    #pragma unroll
    for (int q = 0; q < 4; q++) {
        float4 bi = ((const float4*)bias)[p * 4 + q];
        v[q * 4 + 0] += bi.x; v[q * 4 + 1] += bi.y;
        v[q * 4 + 2] += bi.z; v[q * 4 + 3] += bi.w;
    }
    float s = 0.f, ss = 0.f;
    #pragma unroll
    for (int k = 0; k < 16; k++) { s += v[k]; ss += v[k] * v[k]; }
    #pragma unroll
    for (int o = 1; o < 16; o <<= 1) {
        s  += __shfl_xor(s, o, 64);
        ss += __shfl_xor(ss, o, 64);
    }
    float mn = s * (1.f / H_DIM);
    float var = ss * (1.f / H_DIM) - mn * mn;
    float rstd = rsqrtf(var + 1e-5f);
    #pragma unroll
    for (int q = 0; q < 4; q++) {
        float4 ga = ((const float4*)gamma)[p * 4 + q];
        float4 be = ((const float4*)beta)[p * 4 + q];
        v[q * 4 + 0] = fmaxf((v[q * 4 + 0] - mn) * rstd * ga.x + be.x, 0.f);
        v[q * 4 + 1] = fmaxf((v[q * 4 + 1] - mn) * rstd * ga.y + be.y, 0.f);
        v[q * 4 + 2] = fmaxf((v[q * 4 + 2] - mn) * rstd * ga.z + be.z, 0.f);
        v[q * 4 + 3] = fmaxf((v[q * 4 + 3] - mn) * rstd * ga.w + be.w, 0.f);
    }

    if constexpr (POOL) {
        // stage LN rows into LDS (plain stores), then column-parallel reduce + atomics
        float* row = sh + nl * 260;
        #pragma unroll
        for (int k = 0; k < 16; k++) row[p * 16 + k] = v[k];
        if (p == 0) gid_s[nl] = batch[node];
        __syncthreads();
        int t = threadIdx.x;                // column t
        float acc = 0.f;
        int cur = gid_s[0];
        #pragma unroll
        for (int i = 0; i < 16; i++) {
            int g = gid_s[i];
            if (g != cur) {
                atomicAdd(&pooled[(size_t)cur * H_DIM + t], acc);
                acc = 0.f; cur = g;
            }
            acc += sh[i * 260 + t];
        }
        atomicAdd(&pooled[(size_t)cur * H_DIM + t], acc);
    } else {
        unsigned short* op = out + (size_t)node * H_DIM + p * 16;
        uint4 o0, o1;
        o0.x = pack2(v[0], v[1]);   o0.y = pack2(v[2], v[3]);
        o0.z = pack2(v[4], v[5]);   o0.w = pack2(v[6], v[7]);
        o1.x = pack2(v[8], v[9]);   o1.y = pack2(v[10], v[11]);
        o1.z = pack2(v[12], v[13]); o1.w = pack2(v[14], v[15]);
        *(uint4*)op = o0;
        *(uint4*)(op + 8) = o1;
    }
}

// ---------------- FC head ----------------

__global__ __launch_bounds__(256) void fc_kernel(const float* __restrict__ pooled,
                                                 const int* __restrict__ gstart,
                                                 const float* __restrict__ gattr,
                                                 const float* __restrict__ fcW1,
                                                 const float* __restrict__ fcb1,
                                                 const float* __restrict__ fcW2,
                                                 const float* __restrict__ fcb2,
                                                 float* __restrict__ out) {
    __shared__ float zc[H_DIM + A_DIM];
    __shared__ float z1[H_DIM];
    int g = blockIdx.x, t = threadIdx.x;
    int c_i = gstart[g + 1] - gstart[g];
    float c = (float)(c_i > 1 ? c_i : 1);
    zc[t] = pooled[(size_t)g * H_DIM + t] / c;
    if (t < A_DIM) zc[H_DIM + t] = gattr[g * A_DIM + t];
    __syncthreads();
    float s = fcb1[t];
    for (int k = 0; k < H_DIM + A_DIM; k++)
        s += zc[k] * fcW1[(size_t)k * H_DIM + t];
    z1[t] = fmaxf(s, 0.f) * fcW2[t];
    __syncthreads();
    for (int off = 128; off; off >>= 1) {
        if (t < off) z1[t] += z1[t + off];
        __syncthreads();
    }
    if (t == 0) out[g] = z1[0] + fcb2[0];
}

// ---------------- launch ----------------

extern "C" void kernel_launch(void* const* d_in, const int* in_sizes, int n_in,
                              void* d_out, int out_size, void* d_ws, size_t ws_size,
                              hipStream_t stream) {
    const float* x     = (const float*)d_in[0];
    const float* gattr = (const float*)d_in[1];
    const int*   ei    = (const int*)d_in[2];
    const int*   batch = (const int*)d_in[3];
    const float* W1 = (const float*)d_in[4];  const float* b1 = (const float*)d_in[5];
    const float* W2 = (const float*)d_in[6];  const float* b2 = (const float*)d_in[7];
    const float* W3 = (const float*)d_in[8];  const float* b3 = (const float*)d_in[9];
    const float* g1 = (const float*)d_in[10]; const float* be1 = (const float*)d_in[11];
    const float* g2 = (const float*)d_in[12]; const float* be2 = (const float*)d_in[13];
    const float* g3 = (const float*)d_in[14]; const float* be3 = (const float*)d_in[15];
    const float* fcW1 = (const float*)d_in[16]; const float* fcb1 = (const float*)d_in[17];
    const float* fcW2 = (const float*)d_in[18]; const float* fcb2 = (const float*)d_in[19];
    float* out = (float*)d_out;

    char* w = (char*)d_ws;
    unsigned char*  Pb8 = (unsigned char*)w;  w += (size_t)N_NODES * H_DIM;       // P fp8
    unsigned short* Hb  = (unsigned short*)w; w += (size_t)N_NODES * H_DIM * 2;   // h bf16
    unsigned short* Wt2 = (unsigned short*)w; w += (size_t)H_DIM * H_DIM * 2;
    unsigned short* Wt3 = (unsigned short*)w; w += (size_t)H_DIM * H_DIM * 2;
    float* dinv   = (float*)w; w += (size_t)N_NODES * 4;
    float* pooled = (float*)w; w += (size_t)G_NUM * H_DIM * 4;
    int* rowptr   = (int*)w;   w += (size_t)(N_NODES + 4) * 4;
    unsigned int* Hg = (unsigned int*)w;      w += (size_t)256 * NCHUNK * 4;
    unsigned int* Btot = (unsigned int*)w;    w += (size_t)256 * 4;
    unsigned int* bucketBase = (unsigned int*)w; w += (size_t)(NBUCKET + 4) * 4;
    unsigned int* tmp = (unsigned int*)w;     w += (size_t)N_EDGES * 4;
    unsigned short* csr_src = (unsigned short*)w; w += (size_t)N_EDGES * 2;
    int* gstart   = (int*)w;   w += (size_t)(G_NUM + 1) * 4;

    const int* srcp = ei;
    const int* dstp = ei + N_EDGES;

    // ---- fuse0: bucket count + GEMM1 (X*W1 -> fp8 unscaled) + W transposes ----
    {
        const int CB = NCHUNK;                          // 391
        const int GB = (N_NODES + 127) / 128;           // 391
        const int WB = (2 * H_DIM * H_DIM + 511) / 512; // 256
        fuse0_kernel<<<CB + GB + WB, 512, 0, stream>>>(dstp, Hg, x, W1, Pb8, W2, Wt2, W3, Wt3);
    }
    // ---- CSR build ----
    scanH_kernel<<<NBUCKET, 256, 0, stream>>>(Hg, Btot);
    base_kernel<<<1, 256, 0, stream>>>(Btot, bucketBase, batch, gstart, rowptr, pooled);
    scatter_kernel<<<NCHUNK, 512, 0, stream>>>(srcp, dstp, Hg, bucketBase, tmp);
    finalize_kernel<<<NBUCKET, 256, 0, stream>>>(tmp, bucketBase, rowptr, dinv, csr_src);

    int gemm_blocks = (N_NODES + 127) / 128;    // 391
    int gather_blocks = N_NODES / 16;           // 3125

    // ---- layer 1: weighted gather of A*(X*W1) with fused bias+LN+ReLU ----
    gather_ns<true, false><<<gather_blocks, 256, 0, stream>>>(Pb8, Hb, rowptr, csr_src,
                                                              dinv, b1, g1, be1,
                                                              nullptr, nullptr);
    // ---- layer 2 ----
    gemm_f8<<<gemm_blocks, 512, 0, stream>>>(Hb, Wt2, Pb8, dinv, N_NODES, H_DIM);
    gather_ns<false, false><<<gather_blocks, 256, 0, stream>>>(Pb8, Hb, rowptr, csr_src,
                                                               dinv, b2, g2, be2,
                                                               nullptr, nullptr);
    // ---- layer 3 (gather fused with column-parallel pooling; no Hb write) ----
    gemm_f8<<<gemm_blocks, 512, 0, stream>>>(Hb, Wt3, Pb8, dinv, N_NODES, H_DIM);
    gather_ns<false, true><<<gather_blocks, 256, 0, stream>>>(Pb8, nullptr, rowptr, csr_src,
                                                              dinv, b3, g3, be3,
                                                              batch, pooled);
    // ---- FC head ----
    fc_kernel<<<G_NUM, 256, 0, stream>>>(pooled, gstart, gattr, fcW1, fcb1, fcW2, fcb2, out);
}